// Round 1
// baseline (310.435 us; speedup 1.0000x reference)
//
#include <hip/hip_runtime.h>
#include <hip/hip_bf16.h>
#include <hip/hip_fp8.h>

#define FEAT    256
#define KDIM    512   // FEAT + EMBED
#define EMBED   256
#define BATCH   50000
#define NSAMP   25
#define N_NODES 100000
#define NAN_FILL 0.01f

#define NTILE   48    // batch items per block (LDS tile rows)
#define NWAVES  8     // 512-thread blocks: same 49.9KB LDS -> 3 blocks/CU -> 24 waves/CU
#define LSTRIDE 520   // shorts per LDS row: 512 + 8 pad -> 260 words == 4 (mod 32)
                      // => B-frag ds_read_b128 start-bank = 4*(r+q): perfect 8-cycle tiling

typedef __attribute__((ext_vector_type(8))) short  short8;
typedef __attribute__((ext_vector_type(4))) float  floatx4;
typedef __attribute__((ext_vector_type(2))) float  float2v;
typedef __attribute__((ext_vector_type(4))) unsigned short ushort4v;
typedef __attribute__((ext_vector_type(4))) float  float4v;

#if __has_builtin(__builtin_amdgcn_cvt_pk_f32_fp8)
#define PK_FP8_DEC 1
#else
#define PK_FP8_DEC 0
#endif
#if __has_builtin(__builtin_amdgcn_cvt_pk_fp8_f32)
#define PK_FP8_ENC 1
#else
#define PK_FP8_ENC 0
#endif

__device__ inline unsigned short f2bf(float x) {
    __hip_bfloat16 h = __float2bfloat16(x);
    union { __hip_bfloat16 h; unsigned short u; } c; c.h = h;
    return c.u;
}
__device__ inline unsigned char f2fp8(float x) {
    __hip_fp8_e4m3 t(x);
    return (unsigned char)t.__x;
}
__device__ inline float fp8f(unsigned v) {
    __hip_fp8_e4m3 t; t.__x = (unsigned char)v;
    return (float)t;
}

// ---------------- Stage 0: features f32 -> fp8 e4m3 table (25.6 MB) ----------------
__global__ __launch_bounds__(256) void fconv8_kernel(
    const float* __restrict__ F, unsigned char* __restrict__ F8)
{
    const size_t i = ((size_t)blockIdx.x * 256 + threadIdx.x) * 8;
    float4v a = *(const float4v*)(F + i);
    float4v b = *(const float4v*)(F + i + 4);
#if PK_FP8_ENC
    unsigned w0 = (unsigned)__builtin_amdgcn_cvt_pk_fp8_f32(a[0], a[1], 0, false);
    w0 = (unsigned)__builtin_amdgcn_cvt_pk_fp8_f32(a[2], a[3], (int)w0, true);
    unsigned w1 = (unsigned)__builtin_amdgcn_cvt_pk_fp8_f32(b[0], b[1], 0, false);
    w1 = (unsigned)__builtin_amdgcn_cvt_pk_fp8_f32(b[2], b[3], (int)w1, true);
    uint2 o; o.x = w0; o.y = w1;
    *(uint2*)(F8 + i) = o;
#else
    union { unsigned char c[8]; uint2 v; } o;
    o.c[0] = f2fp8(a[0]); o.c[1] = f2fp8(a[1]); o.c[2] = f2fp8(a[2]); o.c[3] = f2fp8(a[3]);
    o.c[4] = f2fp8(b[0]); o.c[5] = f2fp8(b[1]); o.c[6] = f2fp8(b[2]); o.c[7] = f2fp8(b[3]);
    *(uint2*)(F8 + i) = o.v;
#endif
}

// ---------------- Stage 0b: W f32 -> bf16 ----------------
__global__ __launch_bounds__(256) void wconv_kernel(
    const float* __restrict__ W, unsigned short* __restrict__ Wb)
{
    const int i = blockIdx.x * 256 + threadIdx.x;   // grid sized exactly 256*512
    Wb[i] = f2bf(W[i]);
}

// ---------------- Fused: gather+mean -> LDS tile -> MFMA GEMM -> ReLU -> out ----------
// Block: 512 threads (8 waves), NTILE=48 batch items -> LDS 49.9KB -> 3 blocks/CU
// -> 24 waves/CU (was 12): latency-hiding for the random fp8 gathers.
// Phase 1: each wave stages 6 items: self row from f32 F (16B/lane), 25 neighbor rows
//          from fp8 F8 (4B/lane), packed f32 accumulate (v_cvt_pk_f32_fp8 + v_pk_add_f32),
//          bf16 into LDS [48][520].
// Phase 2: out[e,b] = relu(sum_k W[e,k]*C[b,k]); M=256 (wave covers 32 rows),
//          N=48 (3 x 16-col tiles), K=512. A from global (L2-resident W), B from LDS.
// MFMA 16x16x32 bf16 layouts (guide-verified):
//   A: lane holds A[m=lane&15][k=(lane>>4)*8+j]; B: B[k=(lane>>4)*8+j][n=lane&15]
//   D: row=(lane>>4)*4+reg, col=lane&15
__global__ __launch_bounds__(512, 6) void enc_kernel(
    const float* __restrict__ F,            // [N_NODES, 256] f32
    const unsigned char* __restrict__ F8,   // [N_NODES, 256] fp8
    const unsigned short* __restrict__ Wb,  // [256, 512] bf16
    const int* __restrict__ nodes,
    const int* __restrict__ neigh,          // [BATCH, NSAMP]
    float* __restrict__ out)                // [256, BATCH] f32
{
    __shared__ unsigned short cl[NTILE * LSTRIDE];  // 49,920 B -> 3 blocks/CU

    const int lane = threadIdx.x & 63;
    const int wave = threadIdx.x >> 6;
    const int q = lane >> 4;
    const int r = lane & 15;
    const int nbase = blockIdx.x * NTILE;

    // ---- Phase 1: gather + mean into LDS ----
    for (int it = 0; it < NTILE / NWAVES; ++it) {
        const int li = wave * (NTILE / NWAVES) + it;   // LDS row 0..47
        int b = nbase + li;
        if (b >= BATCH) b = BATCH - 1;              // duplicate work, stores guarded

        const int node = nodes[b];                  // wave-uniform
        float4v sv = *(const float4v*)(F + (size_t)node * FEAT + lane * 4);

        const int* nb = neigh + (size_t)b * NSAMP;
        float2v s01 = {0.f, 0.f}, s23 = {0.f, 0.f};
        #pragma unroll
        for (int j = 0; j < NSAMP; ++j) {
            const int idx = nb[j];                  // wave-uniform -> scalar load
            unsigned wv = *(const unsigned*)(F8 + (size_t)idx * FEAT + lane * 4);
#if PK_FP8_DEC
            s01 += __builtin_amdgcn_cvt_pk_f32_fp8((int)wv, false);
            s23 += __builtin_amdgcn_cvt_pk_f32_fp8((int)wv, true);
#else
            s01[0] += fp8f(wv);
            s01[1] += fp8f(wv >> 8);
            s23[0] += fp8f(wv >> 16);
            s23[1] += fp8f(wv >> 24);
#endif
        }
        const float inv = 1.0f / NSAMP;
        float m0 = s01[0] * inv, m1 = s01[1] * inv, m2 = s23[0] * inv, m3 = s23[1] * inv;
        if (m0 != m0) m0 = NAN_FILL;
        if (m1 != m1) m1 = NAN_FILL;
        if (m2 != m2) m2 = NAN_FILL;
        if (m3 != m3) m3 = NAN_FILL;

        unsigned short* row = cl + li * LSTRIDE;
        ushort4v s; s[0] = f2bf(sv[0]); s[1] = f2bf(sv[1]); s[2] = f2bf(sv[2]); s[3] = f2bf(sv[3]);
        *(ushort4v*)(row + lane * 4) = s;
        ushort4v m; m[0] = f2bf(m0); m[1] = f2bf(m1); m[2] = f2bf(m2); m[3] = f2bf(m3);
        *(ushort4v*)(row + FEAT + lane * 4) = m;
    }
    __syncthreads();

    // ---- Phase 2: MFMA GEMM from LDS tile ----
    const int mbase = wave * 32;                    // 8 waves x 32 rows = 256
    const short* Wp = (const short*)Wb;
    const short* cp = (const short*)cl;

    floatx4 acc[2][3] = {};

    for (int k = 0; k < KDIM; k += 32) {
        short8 afr[2], bfr[3];
        #pragma unroll
        for (int mt = 0; mt < 2; ++mt) {
            const short* p = Wp + (size_t)(mbase + mt * 16 + r) * KDIM + k + q * 8;
            afr[mt] = *(const short8*)p;
        }
        #pragma unroll
        for (int nt = 0; nt < 3; ++nt) {
            const short* p = cp + (nt * 16 + r) * LSTRIDE + k + q * 8;
            bfr[nt] = *(const short8*)p;
        }
        #pragma unroll
        for (int mt = 0; mt < 2; ++mt)
            #pragma unroll
            for (int nt = 0; nt < 3; ++nt)
                acc[mt][nt] = __builtin_amdgcn_mfma_f32_16x16x32_bf16(
                    afr[mt], bfr[nt], acc[mt][nt], 0, 0, 0);
    }

    // ---- Epilogue: ReLU + store ----
    #pragma unroll
    for (int mt = 0; mt < 2; ++mt) {
        #pragma unroll
        for (int nt = 0; nt < 3; ++nt) {
            const int col = nbase + nt * 16 + r;
            if (col < BATCH) {
                #pragma unroll
                for (int i = 0; i < 4; ++i) {
                    const int row = mbase + mt * 16 + q * 4 + i;
                    float v = acc[mt][nt][i];
                    out[(size_t)row * BATCH + col] = v > 0.f ? v : 0.f;
                }
            }
        }
    }
}

extern "C" void kernel_launch(void* const* d_in, const int* in_sizes, int n_in,
                              void* d_out, int out_size, void* d_ws, size_t ws_size,
                              hipStream_t stream) {
    const float* features = (const float*)d_in[0];   // [100000, 256] f32
    const float* weight   = (const float*)d_in[1];   // [256, 512] f32
    const int*   nodes    = (const int*)d_in[2];     // [50000]
    const int*   neigh    = (const int*)d_in[3];     // [50000, 25]
    float* out = (float*)d_out;                      // [256, 50000] f32

    unsigned char* F8  = (unsigned char*)d_ws;                         // 25.6 MB
    unsigned short* Wb = (unsigned short*)(F8 + (size_t)N_NODES * FEAT); // +0.25 MB

    fconv8_kernel<<<(N_NODES * FEAT) / (256 * 8), 256, 0, stream>>>(features, F8);
    wconv_kernel<<<(EMBED * KDIM) / 256, 256, 0, stream>>>(weight, Wb);

    const int nblocks = (BATCH + NTILE - 1) / NTILE;  // 1042
    enc_kernel<<<nblocks, 512, 0, stream>>>(features, F8, Wb, nodes, neigh, out);
}

// Round 2
// 262.633 us; speedup vs baseline: 1.1820x; 1.1820x over previous
//
#include <hip/hip_runtime.h>
#include <hip/hip_bf16.h>
#include <hip/hip_fp8.h>

#define FEAT    256
#define KDIM    512   // FEAT + EMBED
#define EMBED   256
#define BATCH   50000
#define NSAMP   25
#define N_NODES 100000
#define NAN_FILL 0.01f

#define NTILE   32    // batch items per block -> LDS 33.3KB -> 4 blocks/CU (16 waves)
#define LSTRIDE 520   // shorts per LDS row: 512 + 8 pad -> 260 words == 4 (mod 32)
                      // => B-frag ds_read_b128 start-bank = 4*(r+q): perfect 8-cycle tiling

typedef __attribute__((ext_vector_type(8))) short  short8;
typedef __attribute__((ext_vector_type(4))) float  floatx4;
typedef __attribute__((ext_vector_type(2))) float  float2v;
typedef __attribute__((ext_vector_type(4))) unsigned short ushort4v;
typedef __attribute__((ext_vector_type(4))) float  float4v;

#if __has_builtin(__builtin_amdgcn_cvt_pk_f32_fp8)
#define PK_FP8_DEC 1
#else
#define PK_FP8_DEC 0
#endif
#if __has_builtin(__builtin_amdgcn_cvt_pk_fp8_f32)
#define PK_FP8_ENC 1
#else
#define PK_FP8_ENC 0
#endif

__device__ inline unsigned short f2bf(float x) {
    __hip_bfloat16 h = __float2bfloat16(x);
    union { __hip_bfloat16 h; unsigned short u; } c; c.h = h;
    return c.u;
}
__device__ inline unsigned char f2fp8(float x) {
    __hip_fp8_e4m3 t(x);
    return (unsigned char)t.__x;
}
__device__ inline float fp8f(unsigned v) {
    __hip_fp8_e4m3 t; t.__x = (unsigned char)v;
    return (float)t;
}

// ---------------- Stage 0: features f32 -> fp8 e4m3 table (25.6 MB) ----------------
__global__ __launch_bounds__(256) void fconv8_kernel(
    const float* __restrict__ F, unsigned char* __restrict__ F8)
{
    const size_t i = ((size_t)blockIdx.x * 256 + threadIdx.x) * 8;
    float4v a = *(const float4v*)(F + i);
    float4v b = *(const float4v*)(F + i + 4);
#if PK_FP8_ENC
    unsigned w0 = (unsigned)__builtin_amdgcn_cvt_pk_fp8_f32(a[0], a[1], 0, false);
    w0 = (unsigned)__builtin_amdgcn_cvt_pk_fp8_f32(a[2], a[3], (int)w0, true);
    unsigned w1 = (unsigned)__builtin_amdgcn_cvt_pk_fp8_f32(b[0], b[1], 0, false);
    w1 = (unsigned)__builtin_amdgcn_cvt_pk_fp8_f32(b[2], b[3], (int)w1, true);
    uint2 o; o.x = w0; o.y = w1;
    *(uint2*)(F8 + i) = o;
#else
    union { unsigned char c[8]; uint2 v; } o;
    o.c[0] = f2fp8(a[0]); o.c[1] = f2fp8(a[1]); o.c[2] = f2fp8(a[2]); o.c[3] = f2fp8(a[3]);
    o.c[4] = f2fp8(b[0]); o.c[5] = f2fp8(b[1]); o.c[6] = f2fp8(b[2]); o.c[7] = f2fp8(b[3]);
    *(uint2*)(F8 + i) = o.v;
#endif
}

// ---------------- Stage 0b: W f32 -> bf16 ----------------
__global__ __launch_bounds__(256) void wconv_kernel(
    const float* __restrict__ W, unsigned short* __restrict__ Wb)
{
    const int i = blockIdx.x * 256 + threadIdx.x;   // grid sized exactly 256*512
    Wb[i] = f2bf(W[i]);
}

// ---------------- Fused: gather+mean -> LDS tile -> MFMA GEMM -> ReLU -> out ----------
// Block: 256 threads (4 waves), NTILE=32 batch items -> LDS 33.3KB -> 4 blocks/CU
// -> 16 waves/CU, __launch_bounds__(256,4) -> 128-VGPR budget.
// Round-1 lesson: per-wave gather MLP (outstanding loads) matters MORE than waves/CU.
// Phase 1: each wave stages 8 items. All 25 neighbor dwords are loaded into a
//          statically-indexed register array FIRST (25 loads in flight, SGPR base +
//          shared lane*4 voffset), then accumulated with packed v_cvt_pk_f32_fp8.
// Phase 2: out[e,b] = relu(sum_k W[e,k]*C[b,k]); M=256 (wave covers 64 rows),
//          N=32 (2 x 16-col tiles), K=512. A from global (L2-resident W), B from LDS.
// MFMA 16x16x32 bf16 layouts (guide-verified):
//   A: lane holds A[m=lane&15][k=(lane>>4)*8+j]; B: B[k=(lane>>4)*8+j][n=lane&15]
//   D: row=(lane>>4)*4+reg, col=lane&15
__global__ __launch_bounds__(256, 4) void enc_kernel(
    const float* __restrict__ F,            // [N_NODES, 256] f32
    const unsigned char* __restrict__ F8,   // [N_NODES, 256] fp8
    const unsigned short* __restrict__ Wb,  // [256, 512] bf16
    const int* __restrict__ nodes,
    const int* __restrict__ neigh,          // [BATCH, NSAMP]
    float* __restrict__ out)                // [256, BATCH] f32
{
    __shared__ unsigned short cl[NTILE * LSTRIDE];  // 33,280 B -> 4 blocks/CU

    const int lane = threadIdx.x & 63;
    const int wave = threadIdx.x >> 6;
    const int q = lane >> 4;
    const int r = lane & 15;
    const int nbase = blockIdx.x * NTILE;

    // ---- Phase 1: gather + mean into LDS ----
    for (int it = 0; it < NTILE / 4; ++it) {
        const int li = wave * (NTILE / 4) + it;     // LDS row 0..31
        int b = nbase + li;
        if (b >= BATCH) b = BATCH - 1;              // duplicate work, stores guarded

        const int node = nodes[b];                  // wave-uniform -> scalar load
        float4v sv = *(const float4v*)(F + (size_t)node * FEAT + lane * 4);

        const int* nb = neigh + (size_t)b * NSAMP;
        int idxs[NSAMP];
        #pragma unroll
        for (int j = 0; j < NSAMP; ++j) idxs[j] = nb[j];   // wave-uniform -> s_load

        // Batch all 25 gathers: independent loads, all in flight before any use.
        unsigned wv[NSAMP];
        #pragma unroll
        for (int j = 0; j < NSAMP; ++j)
            wv[j] = *(const unsigned*)(F8 + (size_t)idxs[j] * FEAT + lane * 4);

        float2v s01 = {0.f, 0.f}, s23 = {0.f, 0.f};
        #pragma unroll
        for (int j = 0; j < NSAMP; ++j) {
#if PK_FP8_DEC
            s01 += __builtin_amdgcn_cvt_pk_f32_fp8((int)wv[j], false);
            s23 += __builtin_amdgcn_cvt_pk_f32_fp8((int)wv[j], true);
#else
            s01[0] += fp8f(wv[j]);
            s01[1] += fp8f(wv[j] >> 8);
            s23[0] += fp8f(wv[j] >> 16);
            s23[1] += fp8f(wv[j] >> 24);
#endif
        }
        const float inv = 1.0f / NSAMP;
        float m0 = s01[0] * inv, m1 = s01[1] * inv, m2 = s23[0] * inv, m3 = s23[1] * inv;
        if (m0 != m0) m0 = NAN_FILL;
        if (m1 != m1) m1 = NAN_FILL;
        if (m2 != m2) m2 = NAN_FILL;
        if (m3 != m3) m3 = NAN_FILL;

        unsigned short* row = cl + li * LSTRIDE;
        ushort4v s; s[0] = f2bf(sv[0]); s[1] = f2bf(sv[1]); s[2] = f2bf(sv[2]); s[3] = f2bf(sv[3]);
        *(ushort4v*)(row + lane * 4) = s;
        ushort4v m; m[0] = f2bf(m0); m[1] = f2bf(m1); m[2] = f2bf(m2); m[3] = f2bf(m3);
        *(ushort4v*)(row + FEAT + lane * 4) = m;
    }
    __syncthreads();

    // ---- Phase 2: MFMA GEMM from LDS tile ----
    const int mbase = wave * 64;                    // 4 waves x 64 rows = 256
    const short* Wp = (const short*)Wb;
    const short* cp = (const short*)cl;

    floatx4 acc[4][2] = {};

    for (int k = 0; k < KDIM; k += 32) {
        short8 afr[4], bfr[2];
        #pragma unroll
        for (int mt = 0; mt < 4; ++mt) {
            const short* p = Wp + (size_t)(mbase + mt * 16 + r) * KDIM + k + q * 8;
            afr[mt] = *(const short8*)p;
        }
        #pragma unroll
        for (int nt = 0; nt < 2; ++nt) {
            const short* p = cp + (nt * 16 + r) * LSTRIDE + k + q * 8;
            bfr[nt] = *(const short8*)p;
        }
        #pragma unroll
        for (int mt = 0; mt < 4; ++mt)
            #pragma unroll
            for (int nt = 0; nt < 2; ++nt)
                acc[mt][nt] = __builtin_amdgcn_mfma_f32_16x16x32_bf16(
                    afr[mt], bfr[nt], acc[mt][nt], 0, 0, 0);
    }

    // ---- Epilogue: ReLU + store ----
    #pragma unroll
    for (int mt = 0; mt < 4; ++mt) {
        #pragma unroll
        for (int nt = 0; nt < 2; ++nt) {
            const int col = nbase + nt * 16 + r;
            if (col < BATCH) {
                #pragma unroll
                for (int i = 0; i < 4; ++i) {
                    const int row = mbase + mt * 16 + q * 4 + i;
                    float v = acc[mt][nt][i];
                    out[(size_t)row * BATCH + col] = v > 0.f ? v : 0.f;
                }
            }
        }
    }
}

extern "C" void kernel_launch(void* const* d_in, const int* in_sizes, int n_in,
                              void* d_out, int out_size, void* d_ws, size_t ws_size,
                              hipStream_t stream) {
    const float* features = (const float*)d_in[0];   // [100000, 256] f32
    const float* weight   = (const float*)d_in[1];   // [256, 512] f32
    const int*   nodes    = (const int*)d_in[2];     // [50000]
    const int*   neigh    = (const int*)d_in[3];     // [50000, 25]
    float* out = (float*)d_out;                      // [256, 50000] f32

    unsigned char* F8  = (unsigned char*)d_ws;                         // 25.6 MB
    unsigned short* Wb = (unsigned short*)(F8 + (size_t)N_NODES * FEAT); // +0.25 MB

    fconv8_kernel<<<(N_NODES * FEAT) / (256 * 8), 256, 0, stream>>>(features, F8);
    wconv_kernel<<<(EMBED * KDIM) / 256, 256, 0, stream>>>(weight, Wb);

    const int nblocks = (BATCH + NTILE - 1) / NTILE;  // 1563
    enc_kernel<<<nblocks, 256, 0, stream>>>(features, F8, Wb, nodes, neigh, out);
}